// Round 4
// baseline (81.557 us; speedup 1.0000x reference)
//
#include <hip/hip_runtime.h>

// Problem constants (from reference): x (4, 4096, 2048) f32; A,B,C,D (2048,) f32.
#define BATCHN 4
#define TLEN   4096
#define DMODEL 2048
#define LOG2D  11
#define CHUNKS 64
#define LOG2CH 6
#define CLEN   64   // TLEN / CHUNKS

// Saturating clamp to +-1e30.
// Deliberately NOT +-FLT_MAX: under fast-math (ninf) the compiler may fold
// clamp-at-FLT_MAX to identity ("finite values can't exceed FLT_MAX"), which
// is what deleted the clamps in earlier rounds. With a 1e30 bound no such
// identity-fold exists, and runtime v_min/v_max scrub +-inf correctly.
// Healthy (non-overflowing) channels: clamp is exact identity -> bit-exact
// fp32 semantics vs the reference.
__device__ __forceinline__ float fin(float v) {
    return fminf(fmaxf(v, -1.0e30f), 1.0e30f);
}

// ---------------------------------------------------------------------------
// Pass 1: per-(b,d,chunk) local scan from s=0; emit chunk-final state (carry).
// Threads: b*chunks*d = 524288. Lane-consecutive d -> fully coalesced rows.
// ---------------------------------------------------------------------------
__global__ __launch_bounds__(256) void ssm_pass1(
    const float* __restrict__ x, const float* __restrict__ A,
    const float* __restrict__ B, float* __restrict__ carry) {
    int g = blockIdx.x * blockDim.x + threadIdx.x;
    int d = g & (DMODEL - 1);
    int rest = g >> LOG2D;
    int c = rest & (CHUNKS - 1);
    int b = rest >> LOG2CH;

    float a = A[d], bb = B[d];
    const float* xp = x + ((size_t)(b * TLEN + c * CLEN) * DMODEL + d);
    float s = 0.f;
#pragma unroll
    for (int i = 0; i < CLEN; ++i) {
        s = fin(a * s + bb * xp[(size_t)i * DMODEL]);
    }
    carry[((size_t)b * CHUNKS + c) * DMODEL + d] = s;
}

// ---------------------------------------------------------------------------
// Pass 2: per-(b,d) serial combine of chunk carries.
//   hin[0] = 0 ; hin[c] = A^CLEN * hin[c-1] + carry[c-1]
// aL >= 0 (it is a^64 via squaring), so aL*h is +-inf at worst, never nan,
// and fin() scrubs it. 8192 threads; tiny traffic.
// ---------------------------------------------------------------------------
__global__ __launch_bounds__(256) void ssm_pass2(
    const float* __restrict__ A, const float* __restrict__ carry,
    float* __restrict__ hin) {
    int g = blockIdx.x * blockDim.x + threadIdx.x;  // [0, BATCHN*DMODEL)
    int d = g & (DMODEL - 1);
    int b = g >> LOG2D;

    float a = A[d];
    float aL = a;
#pragma unroll
    for (int k = 0; k < 6; ++k) aL = fin(aL * aL);  // a^64, kept finite, >= 0

    const float* cp = carry + (size_t)b * CHUNKS * DMODEL + d;
    float* hp = hin + (size_t)b * CHUNKS * DMODEL + d;
    float h = 0.f;
#pragma unroll
    for (int c = 0; c < CHUNKS; ++c) {
        hp[(size_t)c * DMODEL] = h;
        h = fin(aL * h + cp[(size_t)c * DMODEL]);
    }
}

// ---------------------------------------------------------------------------
// Pass 3: per-(b,d,chunk) rescan from corrected initial state; write y.
// |s| <= 1e30 and |a| <= ~5, so no intermediate ever reaches inf here.
// ---------------------------------------------------------------------------
__global__ __launch_bounds__(256) void ssm_pass3(
    const float* __restrict__ x, const float* __restrict__ A,
    const float* __restrict__ B, const float* __restrict__ Cv,
    const float* __restrict__ Dv, const float* __restrict__ hin,
    float* __restrict__ y) {
    int g = blockIdx.x * blockDim.x + threadIdx.x;
    int d = g & (DMODEL - 1);
    int rest = g >> LOG2D;
    int c = rest & (CHUNKS - 1);
    int b = rest >> LOG2CH;

    float a = A[d], bb = B[d], cc = Cv[d], dd = Dv[d];
    size_t base = (size_t)(b * TLEN + c * CLEN) * DMODEL + d;
    const float* xp = x + base;
    float* yp = y + base;

    float s = fin(hin[((size_t)b * CHUNKS + c) * DMODEL + d]);
#pragma unroll
    for (int i = 0; i < CLEN; ++i) {
        float xi = xp[(size_t)i * DMODEL];
        s = fin(a * s + bb * xi);
        yp[(size_t)i * DMODEL] = fin(cc * s + dd * xi);
    }
}

// ---------------------------------------------------------------------------
// Fallback: exact serial scan, one thread per (b,d). Used only if ws_size is
// too small for the chunked path (keeps correctness unconditional).
// ---------------------------------------------------------------------------
__global__ __launch_bounds__(256) void ssm_serial(
    const float* __restrict__ x, const float* __restrict__ A,
    const float* __restrict__ B, const float* __restrict__ Cv,
    const float* __restrict__ Dv, float* __restrict__ y) {
    int g = blockIdx.x * blockDim.x + threadIdx.x;  // [0, BATCHN*DMODEL)
    int d = g & (DMODEL - 1);
    int b = g >> LOG2D;

    float a = A[d], bb = B[d], cc = Cv[d], dd = Dv[d];
    const float* xp = x + (size_t)b * TLEN * DMODEL + d;
    float* yp = y + (size_t)b * TLEN * DMODEL + d;
    float s = 0.f;
    for (int t = 0; t < TLEN; ++t) {
        float xi = xp[(size_t)t * DMODEL];
        s = fin(a * s + bb * xi);
        yp[(size_t)t * DMODEL] = fin(cc * s + dd * xi);
    }
}

extern "C" void kernel_launch(void* const* d_in, const int* in_sizes, int n_in,
                              void* d_out, int out_size, void* d_ws, size_t ws_size,
                              hipStream_t stream) {
    const float* x  = (const float*)d_in[0];
    const float* A  = (const float*)d_in[1];
    const float* B  = (const float*)d_in[2];
    const float* Cv = (const float*)d_in[3];
    const float* Dv = (const float*)d_in[4];
    float* y = (float*)d_out;

    const size_t seg = (size_t)BATCHN * CHUNKS * DMODEL;  // 524288 floats = 2 MiB
    const size_t need = 2 * seg * sizeof(float);          // carry + hin = 4 MiB

    if (ws_size >= need) {
        float* carry = (float*)d_ws;
        float* hin = carry + seg;
        const int n1 = BATCHN * CHUNKS * DMODEL;  // 524288
        const int n2 = BATCHN * DMODEL;           // 8192
        ssm_pass1<<<n1 / 256, 256, 0, stream>>>(x, A, B, carry);
        ssm_pass2<<<n2 / 256, 256, 0, stream>>>(A, carry, hin);
        ssm_pass3<<<n1 / 256, 256, 0, stream>>>(x, A, B, Cv, Dv, hin, y);
    } else {
        const int n2 = BATCHN * DMODEL;
        ssm_serial<<<n2 / 256, 256, 0, stream>>>(x, A, B, Cv, Dv, y);
    }
}

// Round 5
// 74.364 us; speedup vs baseline: 1.0967x; 1.0967x over previous
//
#include <hip/hip_runtime.h>

// Problem constants (from reference): x (4, 4096, 2048) f32; A,B,C,D (2048,) f32.
#define BATCHN 4
#define TLEN   4096
#define DMODEL 2048
#define D4     512        // DMODEL / 4
#define CHUNKS 64
#define CLEN   64         // TLEN / CHUNKS

typedef float f4 __attribute__((ext_vector_type(4)));

// Saturating clamp to +-1e30. NOT +-FLT_MAX: under fast-math (ninf) a
// FLT_MAX-clamp folds to identity and raw inf leaks (rounds 1-3 post-mortem).
// With 1e30 no identity-fold exists; v_min/v_max scrub inf at runtime.
// Healthy channels (|v| < 1e30): exact identity -> exact fp32 semantics.
__device__ __forceinline__ float fin(float v) {
    return fminf(fmaxf(v, -1.0e30f), 1.0e30f);
}
__device__ __forceinline__ f4 fin4(f4 v) {
    f4 r;
    r.x = fin(v.x); r.y = fin(v.y); r.z = fin(v.z); r.w = fin(v.w);
    return r;
}

// ---------------------------------------------------------------------------
// Pass 1: per-(b,chunk,d4) local scan from s=0; emit chunk-final state.
// 131072 threads, float4 lanes -> 1 KiB per wave load instruction.
// ---------------------------------------------------------------------------
__global__ __launch_bounds__(256) void ssm_pass1(
    const float* __restrict__ x, const float* __restrict__ A,
    const float* __restrict__ B, float* __restrict__ carry) {
    int g = blockIdx.x * blockDim.x + threadIdx.x;
    int d4 = g & (D4 - 1);
    int rest = g >> 9;          // log2(D4)
    int c = rest & (CHUNKS - 1);
    int b = rest >> 6;          // log2(CHUNKS)

    const f4 a = ((const f4*)A)[d4];
    const f4 bb = ((const f4*)B)[d4];
    const f4* xp = (const f4*)x + (size_t)(b * TLEN + c * CLEN) * D4 + d4;

    f4 s = {0.f, 0.f, 0.f, 0.f};
#pragma unroll
    for (int i = 0; i < CLEN; ++i) {
        f4 xi = xp[(size_t)i * D4];
        s = fin4(a * s + bb * xi);
    }
    ((f4*)carry)[((size_t)b * CHUNKS + c) * D4 + d4] = s;
}

// ---------------------------------------------------------------------------
// Pass 2 (fused combine + rescan): per-(b,chunk,d4).
// Preamble: fold the <=63 predecessor carries (2 MiB, L2-resident; loop count
// is block-uniform so no divergence) into the chunk's initial state:
//   h = 0; for j<c: h = aL*h + carry[j]   with aL = A^CLEN (6 squarings).
// Then rescan the chunk from h and write y with NON-TEMPORAL stores so the
// 134 MB y write does not evict x from Infinity Cache (keeps pass-2's x
// re-read on-die instead of HBM).
// ---------------------------------------------------------------------------
__global__ __launch_bounds__(256) void ssm_pass2(
    const float* __restrict__ x, const float* __restrict__ A,
    const float* __restrict__ B, const float* __restrict__ Cv,
    const float* __restrict__ Dv, const float* __restrict__ carry,
    float* __restrict__ y) {
    int g = blockIdx.x * blockDim.x + threadIdx.x;
    int d4 = g & (D4 - 1);
    int rest = g >> 9;
    int c = rest & (CHUNKS - 1);
    int b = rest >> 6;

    const f4 a = ((const f4*)A)[d4];
    const f4 bb = ((const f4*)B)[d4];
    const f4 cc = ((const f4*)Cv)[d4];
    const f4 dd = ((const f4*)Dv)[d4];

    // aL = a^CLEN, kept finite (>=0 by construction).
    f4 aL = a;
#pragma unroll
    for (int k = 0; k < 6; ++k) aL = fin4(aL * aL);

    // Chunk-prefix combine over predecessor carries.
    const f4* cp = (const f4*)carry + (size_t)b * CHUNKS * D4 + d4;
    f4 h = {0.f, 0.f, 0.f, 0.f};
    for (int j = 0; j < c; ++j) {
        f4 cj = cp[(size_t)j * D4];
        h = fin4(aL * h + cj);
    }

    // Rescan chunk from corrected initial state; stream y out non-temporally.
    size_t base = (size_t)(b * TLEN + c * CLEN) * D4 + d4;
    const f4* xp = (const f4*)x + base;
    f4* yp = (f4*)y + base;
    f4 s = h;
#pragma unroll
    for (int i = 0; i < CLEN; ++i) {
        f4 xi = xp[(size_t)i * D4];
        s = fin4(a * s + bb * xi);
        f4 yv = fin4(cc * s + dd * xi);
        __builtin_nontemporal_store(yv, yp + (size_t)i * D4);
    }
}

// ---------------------------------------------------------------------------
// Fallback: exact serial scan, one thread per (b,d). Used only if ws_size is
// too small for the chunked path (keeps correctness unconditional).
// ---------------------------------------------------------------------------
__global__ __launch_bounds__(256) void ssm_serial(
    const float* __restrict__ x, const float* __restrict__ A,
    const float* __restrict__ B, const float* __restrict__ Cv,
    const float* __restrict__ Dv, float* __restrict__ y) {
    int g = blockIdx.x * blockDim.x + threadIdx.x;  // [0, BATCHN*DMODEL)
    int d = g & (DMODEL - 1);
    int b = g >> 11;

    float a = A[d], bb = B[d], cc = Cv[d], dd = Dv[d];
    const float* xp = x + (size_t)b * TLEN * DMODEL + d;
    float* yp = y + (size_t)b * TLEN * DMODEL + d;
    float s = 0.f;
    for (int t = 0; t < TLEN; ++t) {
        float xi = xp[(size_t)t * DMODEL];
        s = fin(a * s + bb * xi);
        yp[(size_t)t * DMODEL] = fin(cc * s + dd * xi);
    }
}

extern "C" void kernel_launch(void* const* d_in, const int* in_sizes, int n_in,
                              void* d_out, int out_size, void* d_ws, size_t ws_size,
                              hipStream_t stream) {
    const float* x  = (const float*)d_in[0];
    const float* A  = (const float*)d_in[1];
    const float* B  = (const float*)d_in[2];
    const float* Cv = (const float*)d_in[3];
    const float* Dv = (const float*)d_in[4];
    float* y = (float*)d_out;

    const size_t need = (size_t)BATCHN * CHUNKS * DMODEL * sizeof(float);  // 2 MiB

    if (ws_size >= need) {
        float* carry = (float*)d_ws;
        const int nthreads = BATCHN * CHUNKS * D4;  // 131072
        ssm_pass1<<<nthreads / 256, 256, 0, stream>>>(x, A, B, carry);
        ssm_pass2<<<nthreads / 256, 256, 0, stream>>>(x, A, B, Cv, Dv, carry, y);
    } else {
        const int n2 = BATCHN * DMODEL;
        ssm_serial<<<n2 / 256, 256, 0, stream>>>(x, A, B, Cv, Dv, y);
    }
}

// Round 6
// 74.092 us; speedup vs baseline: 1.1008x; 1.0037x over previous
//
#include <hip/hip_runtime.h>

// Problem constants (from reference): x (4, 4096, 2048) f32; A,B,C,D (2048,) f32.
#define BATCHN 4
#define TLEN   4096
#define DMODEL 2048
#define D4     512        // DMODEL / 4
#define LOG2D4 9
#define CHUNKS 128
#define LOG2CH 7
#define CLEN   32         // TLEN / CHUNKS

typedef float f4 __attribute__((ext_vector_type(4)));

// Saturating clamp to +-1e30. NOT +-FLT_MAX: under fast-math (ninf) a
// FLT_MAX-clamp folds to identity and raw inf leaks (rounds 1-3 post-mortem).
// With 1e30 no identity-fold exists; v_min/v_max scrub inf at runtime.
// Healthy channels (|v| < 1e30): exact identity -> exact fp32 semantics.
__device__ __forceinline__ float fin(float v) {
    return fminf(fmaxf(v, -1.0e30f), 1.0e30f);
}
__device__ __forceinline__ f4 fin4(f4 v) {
    f4 r;
    r.x = fin(v.x); r.y = fin(v.y); r.z = fin(v.z); r.w = fin(v.w);
    return r;
}

// ---------------------------------------------------------------------------
// Pass 1: per-(b,chunk,d4) local scan from s=0; emit chunk-final state.
// 262144 threads / 1024 blocks -> 4 waves/SIMD for latency hiding.
// ---------------------------------------------------------------------------
__global__ __launch_bounds__(256) void ssm_pass1(
    const float* __restrict__ x, const float* __restrict__ A,
    const float* __restrict__ B, float* __restrict__ carry) {
    int g = blockIdx.x * blockDim.x + threadIdx.x;
    int d4 = g & (D4 - 1);
    int rest = g >> LOG2D4;
    int c = rest & (CHUNKS - 1);
    int b = rest >> LOG2CH;

    const f4 a = ((const f4*)A)[d4];
    const f4 bb = ((const f4*)B)[d4];
    const f4* xp = (const f4*)x + (size_t)(b * TLEN + c * CLEN) * D4 + d4;

    f4 s = {0.f, 0.f, 0.f, 0.f};
#pragma unroll
    for (int i = 0; i < CLEN; ++i) {
        f4 xi = xp[(size_t)i * D4];
        s = fin4(a * s + bb * xi);
    }
    ((f4*)carry)[((size_t)b * CHUNKS + c) * D4 + d4] = s;
}

// ---------------------------------------------------------------------------
// Pass 2 (fused combine + rescan): per-(b,chunk,d4).
// Preamble folds the <=127 predecessor carries (4 MiB, L2-resident) into the
// chunk's initial state: h = 0; for j<c: h = aL*h + carry[j], aL = A^CLEN.
// Unrolled x8 so 8 carry loads are in flight per dependent-FMA group
// (the R5 version's rolled loop serialized ~c x L2-latency).
// Then rescan from h; y goes out via NON-TEMPORAL stores so the 134 MB write
// doesn't evict x from Infinity Cache (x re-read stays on-die).
// ---------------------------------------------------------------------------
__global__ __launch_bounds__(256) void ssm_pass2(
    const float* __restrict__ x, const float* __restrict__ A,
    const float* __restrict__ B, const float* __restrict__ Cv,
    const float* __restrict__ Dv, const float* __restrict__ carry,
    float* __restrict__ y) {
    int g = blockIdx.x * blockDim.x + threadIdx.x;
    int d4 = g & (D4 - 1);
    int rest = g >> LOG2D4;
    int c = rest & (CHUNKS - 1);
    int b = rest >> LOG2CH;

    const f4 a = ((const f4*)A)[d4];
    const f4 bb = ((const f4*)B)[d4];
    const f4 cc = ((const f4*)Cv)[d4];
    const f4 dd = ((const f4*)Dv)[d4];

    // aL = a^CLEN (5 squarings for CLEN=32), kept finite, >= 0.
    f4 aL = a;
#pragma unroll
    for (int k = 0; k < 5; ++k) aL = fin4(aL * aL);

    // Chunk-prefix combine over predecessor carries (block-uniform count).
    const f4* cp = (const f4*)carry + (size_t)b * CHUNKS * D4 + d4;
    f4 h = {0.f, 0.f, 0.f, 0.f};
    int j = 0;
    for (; j + 8 <= c; j += 8) {
        f4 c0 = cp[(size_t)(j + 0) * D4];
        f4 c1 = cp[(size_t)(j + 1) * D4];
        f4 c2 = cp[(size_t)(j + 2) * D4];
        f4 c3 = cp[(size_t)(j + 3) * D4];
        f4 c4 = cp[(size_t)(j + 4) * D4];
        f4 c5 = cp[(size_t)(j + 5) * D4];
        f4 c6 = cp[(size_t)(j + 6) * D4];
        f4 c7 = cp[(size_t)(j + 7) * D4];
        h = fin4(aL * h + c0);
        h = fin4(aL * h + c1);
        h = fin4(aL * h + c2);
        h = fin4(aL * h + c3);
        h = fin4(aL * h + c4);
        h = fin4(aL * h + c5);
        h = fin4(aL * h + c6);
        h = fin4(aL * h + c7);
    }
    for (; j < c; ++j) {
        h = fin4(aL * h + cp[(size_t)j * D4]);
    }

    // Rescan chunk from corrected initial state; stream y out non-temporally.
    size_t base = (size_t)(b * TLEN + c * CLEN) * D4 + d4;
    const f4* xp = (const f4*)x + base;
    f4* yp = (f4*)y + base;
    f4 s = h;
#pragma unroll
    for (int i = 0; i < CLEN; ++i) {
        f4 xi = xp[(size_t)i * D4];
        s = fin4(a * s + bb * xi);
        f4 yv = fin4(cc * s + dd * xi);
        __builtin_nontemporal_store(yv, yp + (size_t)i * D4);
    }
}

// ---------------------------------------------------------------------------
// Fallback: exact serial scan, one thread per (b,d). Used only if ws_size is
// too small for the chunked path (keeps correctness unconditional).
// ---------------------------------------------------------------------------
__global__ __launch_bounds__(256) void ssm_serial(
    const float* __restrict__ x, const float* __restrict__ A,
    const float* __restrict__ B, const float* __restrict__ Cv,
    const float* __restrict__ Dv, float* __restrict__ y) {
    int g = blockIdx.x * blockDim.x + threadIdx.x;  // [0, BATCHN*DMODEL)
    int d = g & (DMODEL - 1);
    int b = g >> 11;

    float a = A[d], bb = B[d], cc = Cv[d], dd = Dv[d];
    const float* xp = x + (size_t)b * TLEN * DMODEL + d;
    float* yp = y + (size_t)b * TLEN * DMODEL + d;
    float s = 0.f;
    for (int t = 0; t < TLEN; ++t) {
        float xi = xp[(size_t)t * DMODEL];
        s = fin(a * s + bb * xi);
        yp[(size_t)t * DMODEL] = fin(cc * s + dd * xi);
    }
}

extern "C" void kernel_launch(void* const* d_in, const int* in_sizes, int n_in,
                              void* d_out, int out_size, void* d_ws, size_t ws_size,
                              hipStream_t stream) {
    const float* x  = (const float*)d_in[0];
    const float* A  = (const float*)d_in[1];
    const float* B  = (const float*)d_in[2];
    const float* Cv = (const float*)d_in[3];
    const float* Dv = (const float*)d_in[4];
    float* y = (float*)d_out;

    const size_t need = (size_t)BATCHN * CHUNKS * DMODEL * sizeof(float);  // 4 MiB

    if (ws_size >= need) {
        float* carry = (float*)d_ws;
        const int nthreads = BATCHN * CHUNKS * D4;  // 262144
        ssm_pass1<<<nthreads / 256, 256, 0, stream>>>(x, A, B, carry);
        ssm_pass2<<<nthreads / 256, 256, 0, stream>>>(x, A, B, Cv, Dv, carry, y);
    } else {
        const int n2 = BATCHN * DMODEL;
        ssm_serial<<<n2 / 256, 256, 0, stream>>>(x, A, B, Cv, Dv, y);
    }
}